// Round 1
// baseline (9378.838 us; speedup 1.0000x reference)
//
#include <hip/hip_runtime.h>
#include <math.h>

#define BB 2
#define TT_SEQ 1024
#define CDIM 1024
#define NH 16
#define NL 4
#define HD 64
#define NTOK (BB*TT_SEQ)   // 2048
#define VOCAB 50257

typedef __bf16 bf16x8 __attribute__((ext_vector_type(8)));
typedef float  f32x4  __attribute__((ext_vector_type(4)));

__device__ __forceinline__ float wave_sum(float v) {
#pragma unroll
    for (int o = 32; o; o >>= 1) v += __shfl_xor(v, o, 64);
    return v;
}

// -------- embedding: x[row,c] = tok_emb[idx[row],c] + pos_emb[row%T,c] ------
__global__ void embed_kernel(const int* __restrict__ idx,
                             const float* __restrict__ tok,
                             const float* __restrict__ pos,
                             float* __restrict__ x) {
    int row = blockIdx.x;          // 0..NTOK-1
    int t = row % TT_SEQ;
    int tokid = idx[row];
    const float4* te = (const float4*)(tok + (size_t)tokid * CDIM);
    const float4* pe = (const float4*)(pos + (size_t)t * CDIM);
    float4* xr = (float4*)(x + (size_t)row * CDIM);
    float4 a = te[threadIdx.x];
    float4 b = pe[threadIdx.x];
    a.x += b.x; a.y += b.y; a.z += b.z; a.w += b.w;
    xr[threadIdx.x] = a;
}

// -------- layernorm over C=1024, one block (256 thr) per row ---------------
__global__ void ln_kernel(const float* __restrict__ x,
                          const float* __restrict__ w,
                          const float* __restrict__ b,
                          float* __restrict__ out) {
    int row = blockIdx.x;
    int tid = threadIdx.x;
    int wid = tid >> 6, lane = tid & 63;
    __shared__ float red[8];
    float4 v = ((const float4*)(x + (size_t)row * CDIM))[tid];
    float s = v.x + v.y + v.z + v.w;
    s = wave_sum(s);
    if (lane == 0) red[wid] = s;
    __syncthreads();
    float mu = (red[0] + red[1] + red[2] + red[3]) * (1.0f / CDIM);
    float dx = v.x - mu, dy = v.y - mu, dz = v.z - mu, dw = v.w - mu;
    float s2 = dx*dx + dy*dy + dz*dz + dw*dw;
    s2 = wave_sum(s2);
    if (lane == 0) red[4 + wid] = s2;
    __syncthreads();
    float var = (red[4] + red[5] + red[6] + red[7]) * (1.0f / CDIM);
    float rs = rsqrtf(var + 1e-5f);
    float4 wv = ((const float4*)w)[tid];
    float4 bv = ((const float4*)b)[tid];
    float4 o;
    o.x = dx * rs * wv.x + bv.x;
    o.y = dy * rs * wv.y + bv.y;
    o.z = dz * rs * wv.z + bv.z;
    o.w = dw * rs * wv.w + bv.w;
    ((float4*)(out + (size_t)row * CDIM))[tid] = o;
}

// -------- split fp32 -> (hi,lo) bf16 pair, packed two-at-a-time ------------
// hi = truncate-to-bf16(a) (exact subtraction residual), lo = trunc-bf16(a-hi)
// combined mantissa ~16 bits -> per-element rel err ~2^-14 (fp32-class here).
__device__ __forceinline__ void split_pack(float a0, float a1,
                                           unsigned int& hp, unsigned int& lp) {
    unsigned int u0 = __float_as_uint(a0), u1 = __float_as_uint(a1);
    float l0 = a0 - __uint_as_float(u0 & 0xffff0000u);
    float l1 = a1 - __uint_as_float(u1 & 0xffff0000u);
    hp = (u0 >> 16) | (u1 & 0xffff0000u);
    lp = (__float_as_uint(l0) >> 16) | (__float_as_uint(l1) & 0xffff0000u);
}

// -------- NT GEMM via split-bf16 MFMA --------------------------------------
// out[n,m] = sum_k A[n,k]*W[m,k]  (+bias)(gelu)(+resid)
// mode bit0: +bias[m]; bit1: exact gelu; bit2: +resid
// Tile: BM = WR*64 rows x 128 cols, BK=32. 256 threads = 4 waves (WR x WC).
// Each product done as hi*hi + hi*lo + lo*hi (3x mfma_f32_16x16x32_bf16).
template<int WR>
__global__ __launch_bounds__(256, 2)
void gemm_nt_mfma(const float* __restrict__ A,
                  const float* __restrict__ W,
                  const float* __restrict__ bias,
                  const float* __restrict__ resid,
                  float* __restrict__ out,
                  int M, int K, int mode) {
    constexpr int BM  = WR * 64;     // output-row tile (64 or 128)
    constexpr int WC  = 4 / WR;      // waves along m (2 or 4)
    constexpr int FN  = 8 / WC;      // 16-wide col frags per wave (4 or 2)
    constexpr int TPR = 256 / BM;    // threads per A row (2 or 4)
    constexpr int AF  = 32 / TPR;    // fp32 elems per thread for A (16 or 8)
    constexpr int LDK = 40;          // padded LDS row stride (u16): 80B, conflict-free

    __shared__ unsigned short Ah[BM][LDK], Al[BM][LDK];
    __shared__ unsigned short Wh[128][LDK], Wl[128][LDK];

    int tid  = threadIdx.x;
    int lane = tid & 63, wid = tid >> 6;
    int wr = wid / WC, wc = wid % WC;
    int n0 = blockIdx.x * BM, m0 = blockIdx.y * 128;

    int arow = tid / TPR, akoff = (tid % TPR) * AF;
    int wrow = tid >> 1,  wkoff = (tid & 1) * 16;
    const float* Ap = A + (size_t)(n0 + arow) * K + akoff;
    const float* Wp = W + (size_t)(m0 + wrow) * K + wkoff;
    bool wvalid = (m0 + wrow) < M;

    f32x4 zero = {0.f, 0.f, 0.f, 0.f};
    f32x4 acc[4][FN];
#pragma unroll
    for (int i = 0; i < 4; i++)
#pragma unroll
        for (int j = 0; j < FN; j++) acc[i][j] = zero;

    // prefetch k0 = 0
    float areg[AF], wreg[16];
#pragma unroll
    for (int i = 0; i < AF; i += 4)
        *(float4*)&areg[i] = *(const float4*)(Ap + i);
#pragma unroll
    for (int i = 0; i < 16; i += 4)
        *(float4*)&wreg[i] = wvalid ? *(const float4*)(Wp + i)
                                    : make_float4(0.f, 0.f, 0.f, 0.f);

    const int ka = (lane >> 4) * 8;   // k-offset of this lane's fragment slice
    const int fr = lane & 15;         // row (A) / col (B) within a 16x16 frag

    for (int k0 = 0; k0 < K; k0 += 32) {
        // convert the staged fp32 to packed (hi,lo) bf16 pairs
        unsigned int ahp[AF/2], alp[AF/2], whp[8], wlp[8];
#pragma unroll
        for (int i = 0; i < AF/2; i++)
            split_pack(areg[2*i], areg[2*i+1], ahp[i], alp[i]);
#pragma unroll
        for (int i = 0; i < 8; i++)
            split_pack(wreg[2*i], wreg[2*i+1], whp[i], wlp[i]);

        __syncthreads();   // previous compute done reading LDS
#pragma unroll
        for (int i = 0; i < AF/2; i += 4) {
            *(uint4*)&Ah[arow][akoff + 2*i] = *(uint4*)&ahp[i];
            *(uint4*)&Al[arow][akoff + 2*i] = *(uint4*)&alp[i];
        }
#pragma unroll
        for (int i = 0; i < 8; i += 4) {
            *(uint4*)&Wh[wrow][wkoff + 2*i] = *(uint4*)&whp[i];
            *(uint4*)&Wl[wrow][wkoff + 2*i] = *(uint4*)&wlp[i];
        }
        __syncthreads();

        // prefetch next K-panel while computing this one
        if (k0 + 32 < K) {
            Ap += 32; Wp += 32;
#pragma unroll
            for (int i = 0; i < AF; i += 4)
                *(float4*)&areg[i] = *(const float4*)(Ap + i);
#pragma unroll
            for (int i = 0; i < 16; i += 4)
                *(float4*)&wreg[i] = wvalid ? *(const float4*)(Wp + i)
                                            : make_float4(0.f, 0.f, 0.f, 0.f);
        }

        bf16x8 bh[FN], bl[FN];
#pragma unroll
        for (int j = 0; j < FN; j++) {
            bh[j] = *(const bf16x8*)&Wh[wc*FN*16 + j*16 + fr][ka];
            bl[j] = *(const bf16x8*)&Wl[wc*FN*16 + j*16 + fr][ka];
        }
#pragma unroll
        for (int i = 0; i < 4; i++) {
            bf16x8 ah = *(const bf16x8*)&Ah[wr*64 + i*16 + fr][ka];
            bf16x8 al = *(const bf16x8*)&Al[wr*64 + i*16 + fr][ka];
#pragma unroll
            for (int j = 0; j < FN; j++) {
                acc[i][j] = __builtin_amdgcn_mfma_f32_16x16x32_bf16(ah, bh[j], acc[i][j], 0, 0, 0);
                acc[i][j] = __builtin_amdgcn_mfma_f32_16x16x32_bf16(ah, bl[j], acc[i][j], 0, 0, 0);
                acc[i][j] = __builtin_amdgcn_mfma_f32_16x16x32_bf16(al, bh[j], acc[i][j], 0, 0, 0);
            }
        }
    }

    // epilogue: C/D layout col=lane&15, row=(lane>>4)*4+reg  [m89/m91]
    const int cr = (lane >> 4) * 4;
#pragma unroll
    for (int i = 0; i < 4; i++) {
#pragma unroll
        for (int j = 0; j < FN; j++) {
            int m = m0 + wc*FN*16 + j*16 + fr;
            if (m >= M) continue;
            int nbase = n0 + wr*64 + i*16 + cr;
            float bval = (mode & 1) ? bias[m] : 0.f;
#pragma unroll
            for (int r = 0; r < 4; r++) {
                float v = acc[i][j][r] + bval;
                if (mode & 2) v = 0.5f * v * (1.0f + erff(v * 0.70710678118654752f));
                size_t off = (size_t)(nbase + r) * (size_t)M + m;
                if (mode & 4) v += resid[off];
                out[off] = v;
            }
        }
    }
}

// -------- attention: wave-per-query-row online softmax ---------------------
__global__ void attn_kernel(const float* __restrict__ q,
                            const float* __restrict__ k,
                            const float* __restrict__ v,
                            float* __restrict__ y) {
    int wid = threadIdx.x >> 6;
    int lane = threadIdx.x & 63;
    int gw = blockIdx.x * 4 + wid;      // (b*NH + h)*T + qpos
    int qpos = gw % TT_SEQ;
    int bh = gw / TT_SEQ;
    int h = bh % NH;
    int b = bh / NH;
    const float scale = 0.125f;         // 1/sqrt(64)
    size_t base = ((size_t)b * TT_SEQ) * CDIM + h * HD + lane;
    float qd = q[base + (size_t)qpos * CDIM] * scale;
    const float* kp = k + base;
    const float* vp = v + base;
    float m = -INFINITY, l = 0.f, acc = 0.f;
    for (int kk = 0; kk <= qpos; kk++) {
        float kv = kp[(size_t)kk * CDIM];
        float s = wave_sum(qd * kv);
        float mn = fmaxf(m, s);
        float alpha = __expf(m - mn);   // exp(-inf)=0 on first iter
        float p = __expf(s - mn);
        l = l * alpha + p;
        acc = acc * alpha + p * vp[(size_t)kk * CDIM];
        m = mn;
    }
    y[base + (size_t)qpos * CDIM] = acc / l;
}

extern "C" void kernel_launch(void* const* d_in, const int* in_sizes, int n_in,
                              void* d_out, int out_size, void* d_ws, size_t ws_size,
                              hipStream_t stream) {
    (void)in_sizes; (void)n_in; (void)out_size; (void)ws_size;
    const int*   idx     = (const int*)d_in[0];
    const float* tok_emb = (const float*)d_in[1];
    const float* pos_emb = (const float*)d_in[2];
    const float* ln1_w   = (const float*)d_in[3];
    const float* ln1_b   = (const float*)d_in[4];
    const float* Wq      = (const float*)d_in[5];
    const float* bq      = (const float*)d_in[6];
    const float* Wk      = (const float*)d_in[7];
    const float* bk      = (const float*)d_in[8];
    const float* Wv      = (const float*)d_in[9];
    const float* bv      = (const float*)d_in[10];
    const float* Wo      = (const float*)d_in[11];
    const float* bo      = (const float*)d_in[12];
    const float* ln2_w   = (const float*)d_in[13];
    const float* ln2_b   = (const float*)d_in[14];
    const float* W1      = (const float*)d_in[15];
    const float* b1      = (const float*)d_in[16];
    const float* W2      = (const float*)d_in[17];
    const float* b2      = (const float*)d_in[18];
    const float* lnf_w   = (const float*)d_in[19];
    const float* lnf_b   = (const float*)d_in[20];
    const float* head_w  = (const float*)d_in[21];
    float* out = (float*)d_out;
    float* ws  = (float*)d_ws;

    const size_t S = (size_t)NTOK * CDIM;   // 2M floats = 8 MB
    float* x  = ws;
    float* h  = ws + S;
    float* qb = ws + 2 * S;
    float* kb = ws + 3 * S;
    float* vb = ws + 4 * S;
    float* yb = ws + 5 * S;
    float* h2 = ws + 6 * S;                 // 4*S floats

    embed_kernel<<<NTOK, 256, 0, stream>>>(idx, tok_emb, pos_emb, x);

    dim3 gA(NTOK / 64, CDIM / 128);              // 32 x 8  (BM=64 tiles)
    dim3 gW1(NTOK / 128, 4 * CDIM / 128);        // 16 x 32 (BM=128)
    for (int l = 0; l < NL; l++) {
        const size_t wcc = (size_t)l * CDIM * CDIM;
        ln_kernel<<<NTOK, 256, 0, stream>>>(x, ln1_w + l * CDIM, ln1_b + l * CDIM, h);
        gemm_nt_mfma<1><<<gA, 256, 0, stream>>>(h, Wq + wcc, bq + l * CDIM, nullptr, qb, CDIM, CDIM, 1);
        gemm_nt_mfma<1><<<gA, 256, 0, stream>>>(h, Wk + wcc, bk + l * CDIM, nullptr, kb, CDIM, CDIM, 1);
        gemm_nt_mfma<1><<<gA, 256, 0, stream>>>(h, Wv + wcc, bv + l * CDIM, nullptr, vb, CDIM, CDIM, 1);
        attn_kernel<<<BB * NH * TT_SEQ / 4, 256, 0, stream>>>(qb, kb, vb, yb);
        gemm_nt_mfma<1><<<gA, 256, 0, stream>>>(yb, Wo + wcc, bo + l * CDIM, x, x, CDIM, CDIM, 1 | 4);
        ln_kernel<<<NTOK, 256, 0, stream>>>(x, ln2_w + l * CDIM, ln2_b + l * CDIM, h);
        gemm_nt_mfma<2><<<gW1, 256, 0, stream>>>(h, W1 + (size_t)l * 4 * CDIM * CDIM,
                                                 b1 + l * 4 * CDIM, nullptr, h2, 4 * CDIM, CDIM, 1 | 2);
        gemm_nt_mfma<1><<<gA, 256, 0, stream>>>(h2, W2 + (size_t)l * CDIM * 4 * CDIM,
                                                b2 + l * CDIM, x, x, CDIM, 4 * CDIM, 1 | 4);
    }
    ln_kernel<<<NTOK, 256, 0, stream>>>(x, lnf_w, lnf_b, h);
    dim3 gh(NTOK / 128, (VOCAB + 127) / 128);    // 16 x 393
    gemm_nt_mfma<2><<<gh, 256, 0, stream>>>(h, head_w, nullptr, nullptr, out, VOCAB, CDIM, 0);
}